// Round 6
// baseline (285.329 us; speedup 1.0000x reference)
//
#include <hip/hip_runtime.h>
#include <math.h>

typedef _Float16 half8 __attribute__((ext_vector_type(8)));
typedef _Float16 half4 __attribute__((ext_vector_type(4)));
typedef __fp16 fp16x2 __attribute__((ext_vector_type(2)));
typedef float floatx4 __attribute__((ext_vector_type(4)));

constexpr int IN_DIM = 36;
constexpr int BLOCKS = 2048;
// Channel map of zxbcdt (152 + pad to 160): z 0..63 (tiles 0-3), xh 64..127
// (tiles 4-7), B 128..135 / C 136..143 (tile 8), dt 144..151 (tile 9 lanes q<2).

__device__ __forceinline__ float fast_rcp(float v) { return __builtin_amdgcn_rcpf(v); }
__device__ __forceinline__ float silu_f(float v) { return v * fast_rcp(1.0f + __expf(-v)); }
__device__ __forceinline__ float softplus_f(float v) {
    return fmaxf(v, 0.0f) + __logf(1.0f + __expf(-fabsf(v)));
}
__device__ __forceinline__ float pk2f(float a, float b) {
    fp16x2 p = __builtin_amdgcn_cvt_pkrtz(a, b);   // v_cvt_pkrtz_f16_f32
    return __builtin_bit_cast(float, p);
}

// ---- prep: 24 fp16 A-operand fragments into d_ws (one block per fragment) ----
// fid 0..19: GEMM1 A = Wc^T (Wc[k][ch] = sum_m f_out_w[m][k]*in_proj_w[ch][m],
//   conv_w folded for ch in [64,144)). Ghost k=36 carries the fully-fused bias.
// fid 20..23: GEMM2 A = out_proj_w[m][k] * norm_w[k] (norm fold).
extern "C" __global__ void __launch_bounds__(64)
prep_kernel(const float* __restrict__ f_out_w, const float* __restrict__ f_out_b,
            const float* __restrict__ in_proj_w, const float* __restrict__ conv_w,
            const float* __restrict__ conv_b, const float* __restrict__ dt_bias,
            const float* __restrict__ norm_w, const float* __restrict__ out_proj_w,
            void* __restrict__ ws) {
    const int fid = blockIdx.x;
    const int L = threadIdx.x;
    const int c = L & 15, q = L >> 4;
    unsigned short* fr = (unsigned short*)ws;
    for (int j = 0; j < 8; ++j) {
        float val = 0.f;
        if (fid < 20) {
            const int t = fid >> 1, ks = fid & 1;
            const int m = t * 16 + c;               // proj channel
            const int k = ks * 32 + q * 8 + j;      // feature
            if (m < 152) {
                if (k < IN_DIM) {
                    float acc = 0.f;
                    for (int mm = 0; mm < 32; ++mm)
                        acc += f_out_w[mm * IN_DIM + k] * in_proj_w[m * 32 + mm];
                    if (m >= 64 && m < 144) acc *= conv_w[(m - 64) * 2 + 1];
                    val = acc;
                } else if (k == IN_DIM) {           // ghost-feature bias slot
                    float acc = 0.f;
                    for (int mm = 0; mm < 32; ++mm)
                        acc += f_out_b[mm] * in_proj_w[m * 32 + mm];
                    if (m >= 64 && m < 144)      val = acc * conv_w[(m - 64) * 2 + 1] + conv_b[m - 64];
                    else if (m >= 144)           val = acc + dt_bias[m - 144];
                    else                         val = acc;
                }
            }
        } else {
            const int mt = (fid - 20) >> 1, ks = (fid - 20) & 1;
            const int m = mt * 16 + c;              // out channel (<32)
            const int k = ks * 32 + q * 8 + j;      // y channel (<64)
            val = out_proj_w[m * 64 + k] * norm_w[k];
        }
        _Float16 h = (_Float16)val;
        fr[fid * 512 + L * 8 + j] = __builtin_bit_cast(unsigned short, h);
    }
}

// ---- main: transposed GEMMs; lane (c,q) owns row c of its 16-row tile ----
extern "C" __global__ void __launch_bounds__(256, 5)
mamba_mfma_kernel(const float* __restrict__ x,
                  const float* __restrict__ D_skip,
                  const void* __restrict__ ws,
                  float* __restrict__ out,
                  int tiles_per_wave) {
    __shared__ _Float16 ldsY[4][16 * 72];          // per-wave y buffer, stride 72 halfs
    const int lane = threadIdx.x & 63;
    const int wv   = threadIdx.x >> 6;
    const int c = lane & 15, q = lane >> 4;

    // static A-operand fragments (weights), ~96 VGPRs
    const char* wsb = (const char*)ws;
    half8 A2[10][2], A3[2][2];
#pragma unroll
    for (int t = 0; t < 10; ++t)
#pragma unroll
        for (int ks = 0; ks < 2; ++ks)
            A2[t][ks] = *(const half8*)(wsb + (size_t)((t * 2 + ks) * 64 + lane) * 16);
#pragma unroll
    for (int mt = 0; mt < 2; ++mt)
#pragma unroll
        for (int ks = 0; ks < 2; ++ks)
            A3[mt][ks] = *(const half8*)(wsb + (size_t)((20 + mt * 2 + ks) * 64 + lane) * 16);

    const float4 dskv = *(const float4*)(D_skip + (q & 1) * 4);  // heads 4(q&1)+r
    _Float16* myL = ldsY[wv];

    const long rowBase = (long)(blockIdx.x * 4 + wv) * tiles_per_wave * 16;
    const float* xrow = x + (rowBase + c) * (long)IN_DIM;

    float4 xa, xb, xct;
    {
        const float* p = xrow + q * 8;
        xa = *(const float4*)p;
        xb = *(const float4*)(p + 4);
        xct = (q == 0) ? *(const float4*)(xrow + 32) : make_float4(0.f, 0.f, 0.f, 0.f);
    }

#pragma unroll 1
    for (int tile = 0; tile < tiles_per_wave; ++tile) {
        float4 na = xa, nb = xb, nc2 = xct;
        if (tile + 1 < tiles_per_wave) {
            const float* p = xrow + (size_t)(tile + 1) * 16 * IN_DIM + q * 8;
            na = *(const float4*)p;
            nb = *(const float4*)(p + 4);
            if (q == 0) nc2 = *(const float4*)(xrow + (size_t)(tile + 1) * 16 * IN_DIM + 32);
        }

        // B-operand from x, packed with v_cvt_pkrtz (2 floats/op)
        union { half8 h; float4 f; } bx0, bx1;
        bx0.f.x = pk2f(xa.x, xa.y);
        bx0.f.y = pk2f(xa.z, xa.w);
        bx0.f.z = pk2f(xb.x, xb.y);
        bx0.f.w = pk2f(xb.z, xb.w);
        bx1.f.x = pk2f(xct.x, xct.y);               // xct already 0 for q!=0
        bx1.f.y = pk2f(xct.z, xct.w);
        bx1.f.z = (q == 0) ? pk2f(1.0f, 0.0f) : 0.0f;  // ghost feature -> bias
        bx1.f.w = 0.0f;

        // GEMM1 transposed: acc[t] lane (c,q) reg r = channel 16t+4q+r, row c
        floatx4 acc[10];
#pragma unroll
        for (int t = 0; t < 10; ++t) {
            floatx4 z4 = {0.f, 0.f, 0.f, 0.f};
            z4 = __builtin_amdgcn_mfma_f32_16x16x32_f16(A2[t][0], bx0.h, z4, 0, 0, 0);
            acc[t] = __builtin_amdgcn_mfma_f32_16x16x32_f16(A2[t][1], bx1.h, z4, 0, 0, 0);
        }

        // conv+silu only on B/C (tile 8); z/xh silus are fused below
#pragma unroll
        for (int r = 0; r < 4; ++r) acc[8][r] = silu_f(acc[8][r]);

        // bc: tile 8 = B (q<2) / C (q>=2); xor32 pairs same s, in-lane sum, xor16 combine
        float recv[4];
#pragma unroll
        for (int r = 0; r < 4; ++r) recv[r] = __shfl_xor(acc[8][r], 32, 64);
        float part = 0.f;
#pragma unroll
        for (int r = 0; r < 4; ++r) part = __builtin_fmaf(acc[8][r], recv[r], part);
        const float bc = part + __shfl_xor(part, 16, 64);

        // scale per head (valid in q<2: q=0 heads 0..3, q=1 heads 4..7)
        float scale[4];
#pragma unroll
        for (int r = 0; r < 4; ++r)
            scale[r] = __builtin_fmaf(softplus_f(acc[9][r]), bc, dskv[r]);
        // broadcast the 8 head scales from lanes (c,0) and (c,1)
        float s0[4], s1[4];
#pragma unroll
        for (int r = 0; r < 4; ++r) {
            s0[r] = __shfl(scale[r], c, 64);
            s1[r] = __shfl(scale[r], c + 16, 64);
        }
        const bool hb = (q >= 2);                  // head parity for this lane's channels
        float sclA[4];
        sclA[0] = hb ? s0[1] : s0[0];
        sclA[1] = hb ? s0[3] : s0[2];
        sclA[2] = hb ? s1[1] : s1[0];
        sclA[3] = hb ? s1[3] : s1[2];

        // y = silu(xh_conv)*scale*silu(z), with the two rcps fused into one:
        // silu(a)*silu(b) = a*b*rcp((1+e^-a)(1+e^-b)). sumsq via 2 shuffles.
        float yv[4][4];
        float ssum = 0.f;
#pragma unroll
        for (int t = 0; t < 4; ++t)
#pragma unroll
            for (int r = 0; r < 4; ++r) {
                const float zr = acc[t][r], xh = acc[4 + t][r];
                const float den = (1.0f + __expf(-zr)) * (1.0f + __expf(-xh));
                const float v = zr * xh * sclA[t] * fast_rcp(den);
                yv[t][r] = v;
                ssum = __builtin_fmaf(v, v, ssum);
            }
        ssum += __shfl_xor(ssum, 16, 64);
        ssum += __shfl_xor(ssum, 32, 64);
        const float rs = __builtin_amdgcn_rsqf(__builtin_fmaf(ssum, 1.0f / 64.0f, 1e-5f));

        // y -> LDS (half, stride 72) -> B-operand for GEMM2
#pragma unroll
        for (int t = 0; t < 4; ++t) {
            union { half4 h; float2 f; } w;
            w.f.x = pk2f(yv[t][0], yv[t][1]);
            w.f.y = pk2f(yv[t][2], yv[t][3]);
            *(half4*)(myL + c * 72 + 16 * t + 4 * q) = w.h;
        }
        half8 By0 = *(const half8*)(myL + c * 72 + 8 * q);
        half8 By1 = *(const half8*)(myL + c * 72 + 32 + 8 * q);

        // GEMM2 transposed: logits^T; lane (c,q) reg r = out-ch {4q+r, 16+4q+r}, row c
        floatx4 z4 = {0.f, 0.f, 0.f, 0.f};
        floatx4 lg0 = __builtin_amdgcn_mfma_f32_16x16x32_f16(A3[0][0], By0, z4, 0, 0, 0);
        lg0 = __builtin_amdgcn_mfma_f32_16x16x32_f16(A3[0][1], By1, lg0, 0, 0, 0);
        floatx4 lg1 = __builtin_amdgcn_mfma_f32_16x16x32_f16(A3[1][0], By0, z4, 0, 0, 0);
        lg1 = __builtin_amdgcn_mfma_f32_16x16x32_f16(A3[1][1], By1, lg1, 0, 0, 0);

        // softmax over 32 out-chs; max-pass skipped (|logit*rs| small, fp32-safe);
        // log2e folded into rs so each exp is a single v_exp_f32 after one mul.
        const float rs2 = rs * 1.44269504f;
        float e0[4], e1[4];
        float lsum = 0.f;
#pragma unroll
        for (int r = 0; r < 4; ++r) {
            e0[r] = __builtin_amdgcn_exp2f(lg0[r] * rs2);
            e1[r] = __builtin_amdgcn_exp2f(lg1[r] * rs2);
            lsum += e0[r] + e1[r];
        }
        lsum += __shfl_xor(lsum, 16, 64);
        lsum += __shfl_xor(lsum, 32, 64);
        const float inv = fast_rcp(lsum);

        const long orow = rowBase + (long)tile * 16 + c;
        *(float4*)(out + orow * 32 + 4 * q) =
            make_float4(e0[0] * inv, e0[1] * inv, e0[2] * inv, e0[3] * inv);
        *(float4*)(out + orow * 32 + 16 + 4 * q) =
            make_float4(e1[0] * inv, e1[1] * inv, e1[2] * inv, e1[3] * inv);

        xa = na; xb = nb; xct = nc2;
    }
}

extern "C" void kernel_launch(void* const* d_in, const int* in_sizes, int n_in,
                              void* d_out, int out_size, void* d_ws, size_t ws_size,
                              hipStream_t stream) {
    const float* x          = (const float*)d_in[0];
    const float* f_out_w    = (const float*)d_in[1];
    const float* f_out_b    = (const float*)d_in[2];
    const float* in_proj_w  = (const float*)d_in[3];
    const float* conv_w     = (const float*)d_in[4];
    const float* conv_b     = (const float*)d_in[5];
    const float* dt_bias    = (const float*)d_in[6];
    // d_in[7] = A_log — unused by the reference
    const float* D_skip     = (const float*)d_in[8];
    const float* norm_w     = (const float*)d_in[9];
    const float* out_proj_w = (const float*)d_in[10];
    float* out = (float*)d_out;

    const int n = in_sizes[0] / IN_DIM;                 // 524288
    const int tiles_per_wave = n / (BLOCKS * 4 * 16);   // 4

    hipLaunchKernelGGL(prep_kernel, dim3(24), dim3(64), 0, stream,
                       f_out_w, f_out_b, in_proj_w, conv_w, conv_b, dt_bias,
                       norm_w, out_proj_w, d_ws);
    hipLaunchKernelGGL(mamba_mfma_kernel, dim3(BLOCKS), dim3(256), 0, stream,
                       x, D_skip, d_ws, out, tiles_per_wave);
}

// Round 7
// 163.585 us; speedup vs baseline: 1.7442x; 1.7442x over previous
//
#include <hip/hip_runtime.h>
#include <math.h>

typedef _Float16 half8 __attribute__((ext_vector_type(8)));
typedef _Float16 half4 __attribute__((ext_vector_type(4)));
typedef __fp16 fp16x2 __attribute__((ext_vector_type(2)));
typedef float floatx4 __attribute__((ext_vector_type(4)));
typedef float floatx2 __attribute__((ext_vector_type(2)));

constexpr int IN_DIM = 36;
constexpr int BLOCKS = 2048;
// Channel map of zxbcdt (152 + pad to 160): z 0..63 (tiles 0-3), xh 64..127
// (tiles 4-7), B 128..135 / C 136..143 (tile 8), dt 144..151 (tile 9 lanes q<2).

__device__ __forceinline__ float fast_rcp(float v) { return __builtin_amdgcn_rcpf(v); }
__device__ __forceinline__ float silu_f(float v) { return v * fast_rcp(1.0f + __expf(-v)); }
__device__ __forceinline__ float softplus_f(float v) {
    return fmaxf(v, 0.0f) + __logf(1.0f + __expf(-fabsf(v)));
}
__device__ __forceinline__ float pk2f(float a, float b) {
    fp16x2 p = __builtin_amdgcn_cvt_pkrtz(a, b);   // v_cvt_pkrtz_f16_f32
    return __builtin_bit_cast(float, p);
}

// ---- prep: 24 fp16 A-operand fragments into d_ws (one block per fragment) ----
// fid 0..19: GEMM1 A = Wc^T (Wc[k][ch] = sum_m f_out_w[m][k]*in_proj_w[ch][m],
//   conv_w folded for ch in [64,144)). Ghost k=36 carries the fully-fused bias.
// fid 20..23: GEMM2 A = out_proj_w[m][k] * norm_w[k] (norm fold).
extern "C" __global__ void __launch_bounds__(64)
prep_kernel(const float* __restrict__ f_out_w, const float* __restrict__ f_out_b,
            const float* __restrict__ in_proj_w, const float* __restrict__ conv_w,
            const float* __restrict__ conv_b, const float* __restrict__ dt_bias,
            const float* __restrict__ norm_w, const float* __restrict__ out_proj_w,
            void* __restrict__ ws) {
    const int fid = blockIdx.x;
    const int L = threadIdx.x;
    const int c = L & 15, q = L >> 4;
    unsigned short* fr = (unsigned short*)ws;
    for (int j = 0; j < 8; ++j) {
        float val = 0.f;
        if (fid < 20) {
            const int t = fid >> 1, ks = fid & 1;
            const int m = t * 16 + c;               // proj channel
            const int k = ks * 32 + q * 8 + j;      // feature
            if (m < 152) {
                if (k < IN_DIM) {
                    float acc = 0.f;
                    for (int mm = 0; mm < 32; ++mm)
                        acc += f_out_w[mm * IN_DIM + k] * in_proj_w[m * 32 + mm];
                    if (m >= 64 && m < 144) acc *= conv_w[(m - 64) * 2 + 1];
                    val = acc;
                } else if (k == IN_DIM) {           // ghost-feature bias slot
                    float acc = 0.f;
                    for (int mm = 0; mm < 32; ++mm)
                        acc += f_out_b[mm] * in_proj_w[m * 32 + mm];
                    if (m >= 64 && m < 144)      val = acc * conv_w[(m - 64) * 2 + 1] + conv_b[m - 64];
                    else if (m >= 144)           val = acc + dt_bias[m - 144];
                    else                         val = acc;
                }
            }
        } else {
            const int mt = (fid - 20) >> 1, ks = (fid - 20) & 1;
            const int m = mt * 16 + c;              // out channel (<32)
            const int k = ks * 32 + q * 8 + j;      // y channel (<64)
            val = out_proj_w[m * 64 + k] * norm_w[k];
        }
        _Float16 h = (_Float16)val;
        fr[fid * 512 + L * 8 + j] = __builtin_bit_cast(unsigned short, h);
    }
}

// ---- main: transposed GEMMs; lane (c,q) owns row c of its 16-row tile ----
extern "C" __global__ void __launch_bounds__(256, 3)
mamba_mfma_kernel(const float* __restrict__ x,
                  const float* __restrict__ D_skip,
                  const void* __restrict__ ws,
                  float* __restrict__ out,
                  int tiles_per_wave) {
    __shared__ _Float16 ldsY[4][16 * 72];          // per-wave y buffer, stride 72 halfs
    const int lane = threadIdx.x & 63;
    const int wv   = threadIdx.x >> 6;
    const int c = lane & 15, q = lane >> 4;

    // static A-operand fragments (weights), ~96 VGPRs
    const char* wsb = (const char*)ws;
    half8 A2[10][2], A3[2][2];
#pragma unroll
    for (int t = 0; t < 10; ++t)
#pragma unroll
        for (int ks = 0; ks < 2; ++ks)
            A2[t][ks] = *(const half8*)(wsb + (size_t)((t * 2 + ks) * 64 + lane) * 16);
#pragma unroll
    for (int mt = 0; mt < 2; ++mt)
#pragma unroll
        for (int ks = 0; ks < 2; ++ks)
            A3[mt][ks] = *(const half8*)(wsb + (size_t)((20 + mt * 2 + ks) * 64 + lane) * 16);

    const float4 dskv = *(const float4*)(D_skip + (q & 1) * 4);  // heads 4(q&1)+r
    _Float16* myL = ldsY[wv];

    const long rowBase = (long)(blockIdx.x * 4 + wv) * tiles_per_wave * 16;
    const float* xrow = x + (rowBase + c) * (long)IN_DIM;

    float4 xa, xb, xct;
    {
        const float* p = xrow + q * 8;
        xa = *(const float4*)p;
        xb = *(const float4*)(p + 4);
        xct = (q == 0) ? *(const float4*)(xrow + 32) : make_float4(0.f, 0.f, 0.f, 0.f);
    }

#pragma unroll 1
    for (int tile = 0; tile < tiles_per_wave; ++tile) {
        float4 na = xa, nb = xb, nc2 = xct;
        if (tile + 1 < tiles_per_wave) {
            const float* p = xrow + (size_t)(tile + 1) * 16 * IN_DIM + q * 8;
            na = *(const float4*)p;
            nb = *(const float4*)(p + 4);
            if (q == 0) nc2 = *(const float4*)(xrow + (size_t)(tile + 1) * 16 * IN_DIM + 32);
        }

        // B-operand from x, packed with v_cvt_pkrtz (2 floats/op); bit_cast keeps
        // everything in registers (unions here caused scratch spills in R6).
        float4 t0, t1;
        t0.x = pk2f(xa.x, xa.y);
        t0.y = pk2f(xa.z, xa.w);
        t0.z = pk2f(xb.x, xb.y);
        t0.w = pk2f(xb.z, xb.w);
        t1.x = pk2f(xct.x, xct.y);                  // xct already 0 for q!=0
        t1.y = pk2f(xct.z, xct.w);
        t1.z = (q == 0) ? pk2f(1.0f, 0.0f) : 0.0f;  // ghost feature -> bias
        t1.w = 0.0f;
        const half8 Bx0 = __builtin_bit_cast(half8, t0);
        const half8 Bx1 = __builtin_bit_cast(half8, t1);

        // GEMM1 transposed: acc[t] lane (c,q) reg r = channel 16t+4q+r, row c
        floatx4 acc[10];
#pragma unroll
        for (int t = 0; t < 10; ++t) {
            floatx4 z4 = {0.f, 0.f, 0.f, 0.f};
            z4 = __builtin_amdgcn_mfma_f32_16x16x32_f16(A2[t][0], Bx0, z4, 0, 0, 0);
            acc[t] = __builtin_amdgcn_mfma_f32_16x16x32_f16(A2[t][1], Bx1, z4, 0, 0, 0);
        }

        // conv+silu only on B/C (tile 8); z/xh silus are fused below
#pragma unroll
        for (int r = 0; r < 4; ++r) acc[8][r] = silu_f(acc[8][r]);

        // bc: tile 8 = B (q<2) / C (q>=2); xor32 pairs same s, in-lane sum, xor16 combine
        float recv[4];
#pragma unroll
        for (int r = 0; r < 4; ++r) recv[r] = __shfl_xor(acc[8][r], 32, 64);
        float part = 0.f;
#pragma unroll
        for (int r = 0; r < 4; ++r) part = __builtin_fmaf(acc[8][r], recv[r], part);
        const float bc = part + __shfl_xor(part, 16, 64);

        // scale per head (valid in q<2: q=0 heads 0..3, q=1 heads 4..7)
        float scale[4];
#pragma unroll
        for (int r = 0; r < 4; ++r)
            scale[r] = __builtin_fmaf(softplus_f(acc[9][r]), bc, dskv[r]);
        // broadcast the 8 head scales from lanes (c,0) and (c,1)
        float s0[4], s1[4];
#pragma unroll
        for (int r = 0; r < 4; ++r) {
            s0[r] = __shfl(scale[r], c, 64);
            s1[r] = __shfl(scale[r], c + 16, 64);
        }
        const bool hb = (q >= 2);                  // head parity for this lane's channels
        float sclA[4];
        sclA[0] = hb ? s0[1] : s0[0];
        sclA[1] = hb ? s0[3] : s0[2];
        sclA[2] = hb ? s1[1] : s1[0];
        sclA[3] = hb ? s1[3] : s1[2];

        // y = silu(xh_conv)*scale*silu(z), with the two rcps fused into one:
        // silu(a)*silu(b) = a*b*rcp((1+e^-a)(1+e^-b)). sumsq via 2 shuffles.
        float yv[4][4];
        float ssum = 0.f;
#pragma unroll
        for (int t = 0; t < 4; ++t)
#pragma unroll
            for (int r = 0; r < 4; ++r) {
                const float zr = acc[t][r], xh = acc[4 + t][r];
                const float den = (1.0f + __expf(-zr)) * (1.0f + __expf(-xh));
                const float v = zr * xh * sclA[t] * fast_rcp(den);
                yv[t][r] = v;
                ssum = __builtin_fmaf(v, v, ssum);
            }
        ssum += __shfl_xor(ssum, 16, 64);
        ssum += __shfl_xor(ssum, 32, 64);
        const float rs = __builtin_amdgcn_rsqf(__builtin_fmaf(ssum, 1.0f / 64.0f, 1e-5f));

        // y -> LDS (half, stride 72) -> B-operand for GEMM2
#pragma unroll
        for (int t = 0; t < 4; ++t) {
            floatx2 w;
            w.x = pk2f(yv[t][0], yv[t][1]);
            w.y = pk2f(yv[t][2], yv[t][3]);
            *(floatx2*)(myL + c * 72 + 16 * t + 4 * q) = w;   // 8B-aligned
        }
        half8 By0 = *(const half8*)(myL + c * 72 + 8 * q);
        half8 By1 = *(const half8*)(myL + c * 72 + 32 + 8 * q);

        // GEMM2 transposed: logits^T; lane (c,q) reg r = out-ch {4q+r, 16+4q+r}, row c
        floatx4 z4 = {0.f, 0.f, 0.f, 0.f};
        floatx4 lg0 = __builtin_amdgcn_mfma_f32_16x16x32_f16(A3[0][0], By0, z4, 0, 0, 0);
        lg0 = __builtin_amdgcn_mfma_f32_16x16x32_f16(A3[0][1], By1, lg0, 0, 0, 0);
        floatx4 lg1 = __builtin_amdgcn_mfma_f32_16x16x32_f16(A3[1][0], By0, z4, 0, 0, 0);
        lg1 = __builtin_amdgcn_mfma_f32_16x16x32_f16(A3[1][1], By1, lg1, 0, 0, 0);

        // softmax over 32 out-chs; max-pass skipped (|logit*rs| small, fp32-safe);
        // log2e folded into rs so each exp is a single v_exp_f32 after one mul.
        const float rs2 = rs * 1.44269504f;
        float e0[4], e1[4];
        float lsum = 0.f;
#pragma unroll
        for (int r = 0; r < 4; ++r) {
            e0[r] = __builtin_amdgcn_exp2f(lg0[r] * rs2);
            e1[r] = __builtin_amdgcn_exp2f(lg1[r] * rs2);
            lsum += e0[r] + e1[r];
        }
        lsum += __shfl_xor(lsum, 16, 64);
        lsum += __shfl_xor(lsum, 32, 64);
        const float inv = fast_rcp(lsum);

        const long orow = rowBase + (long)tile * 16 + c;
        *(float4*)(out + orow * 32 + 4 * q) =
            make_float4(e0[0] * inv, e0[1] * inv, e0[2] * inv, e0[3] * inv);
        *(float4*)(out + orow * 32 + 16 + 4 * q) =
            make_float4(e1[0] * inv, e1[1] * inv, e1[2] * inv, e1[3] * inv);

        xa = na; xb = nb; xct = nc2;
    }
}

extern "C" void kernel_launch(void* const* d_in, const int* in_sizes, int n_in,
                              void* d_out, int out_size, void* d_ws, size_t ws_size,
                              hipStream_t stream) {
    const float* x          = (const float*)d_in[0];
    const float* f_out_w    = (const float*)d_in[1];
    const float* f_out_b    = (const float*)d_in[2];
    const float* in_proj_w  = (const float*)d_in[3];
    const float* conv_w     = (const float*)d_in[4];
    const float* conv_b     = (const float*)d_in[5];
    const float* dt_bias    = (const float*)d_in[6];
    // d_in[7] = A_log — unused by the reference
    const float* D_skip     = (const float*)d_in[8];
    const float* norm_w     = (const float*)d_in[9];
    const float* out_proj_w = (const float*)d_in[10];
    float* out = (float*)d_out;

    const int n = in_sizes[0] / IN_DIM;                 // 524288
    const int tiles_per_wave = n / (BLOCKS * 4 * 16);   // 4

    hipLaunchKernelGGL(prep_kernel, dim3(24), dim3(64), 0, stream,
                       f_out_w, f_out_b, in_proj_w, conv_w, conv_b, dt_bias,
                       norm_w, out_proj_w, d_ws);
    hipLaunchKernelGGL(mamba_mfma_kernel, dim3(BLOCKS), dim3(256), 0, stream,
                       x, D_skip, d_ws, out, tiles_per_wave);
}